// Round 7
// baseline (188.288 us; speedup 1.0000x reference)
//
#include <hip/hip_runtime.h>
#include <hip/hip_bf16.h>

typedef __bf16 bf16;
typedef __bf16 bf16x4 __attribute__((ext_vector_type(4)));
typedef __bf16 bf16x8 __attribute__((ext_vector_type(8)));
typedef float f32x4 __attribute__((ext_vector_type(4)));
typedef unsigned short u16x4 __attribute__((ext_vector_type(4)));

#define B_ 2
#define S_ 2048
#define H_ 16
#define DH_ 64
#define D_ 1024

// Ordering notes (R2 post-mortem): global_load_lds retires on vmcnt, ds_* on
// lgkmcnt. Two edges MUST be explicit:
//   (1) vmcnt(0) before the barrier that publishes freshly staged LDS tiles.
//   (2) lgkmcnt(0) between a wave's own ds_write and its ds_read of the same
//       bytes.
// R6+R8+R14: explicit double-buffering regressed three times.
// R16/R17/R18 isolation matrix: s_setprio present in all three FAILS, absent
// from the PASS (R15). __builtin_amdgcn_s_setprio is BANNED in this kernel /
// compiler combination — it corrupts output nondeterministically.
// Also banned: mid-tile staging phase-split (R16), QK-all->PV-all merge (R17)
// — untestable independently of setprio now; do not reintroduce without an
// .s-level audit.
#define WAIT_VMCNT0() asm volatile("s_waitcnt vmcnt(0)" ::: "memory")
#define WAIT_LGKM0()  asm volatile("s_waitcnt lgkmcnt(0)" ::: "memory")

// async global->LDS, 16B per lane; LDS dest is wave-uniform base + lane*16
__device__ __forceinline__ void gld_lds16(const bf16* g, bf16* l) {
    __builtin_amdgcn_global_load_lds(
        (__attribute__((address_space(1))) void*)g,
        (__attribute__((address_space(3))) void*)l, 16, 0, 0);
}

// fast RNE float->bf16, no NaN/denorm path (inputs are finite, well-scaled)
__device__ __forceinline__ bf16 f2bf(float x) {
    union { float f; unsigned u; } v; v.f = x;
    unsigned short h = (unsigned short)((v.u + 0x7FFF + ((v.u >> 16) & 1)) >> 16);
    return __builtin_bit_cast(bf16, h);
}

// packed f32x2 -> bf16x2 (RNE), single VALU op (no builtin on gfx950, m240)
__device__ __forceinline__ unsigned cvtpk(float lo, float hi) {
    unsigned r;
    asm("v_cvt_pk_bf16_f32 %0, %1, %2" : "=v"(r) : "v"(lo), "v"(hi));
    return r;
}

// v_permlane32_swap_b32: a.row1 <-> b.row0  =>  a'={a.lo32,b.lo32}, b'={a.hi32,b.hi32}
__device__ __forceinline__ void pl32swap(unsigned &a, unsigned &b) {
    asm("v_permlane32_swap_b32 %0, %1" : "+v"(a), "+v"(b));
}
// v_permlane16_swap_b32: odd 16-rows of a <-> even 16-rows of b
__device__ __forceinline__ void pl16swap(unsigned &a, unsigned &b) {
    asm("v_permlane16_swap_b32 %0, %1" : "+v"(a), "+v"(b));
}

// ---------------------------------------------------------------------------
// Kernel 1: fp32 -> bf16 conversion/packing. (unchanged)
// ---------------------------------------------------------------------------
__global__ __launch_bounds__(256) void cvt_kernel(
    const float* __restrict__ hs,
    const float* __restrict__ Wq, const float* __restrict__ Wk,
    const float* __restrict__ Wv, const float* __restrict__ Wo,
    bf16* __restrict__ hsb, bf16* __restrict__ wqkv, bf16* __restrict__ wob)
{
    int i = (blockIdx.x * 256 + threadIdx.x) * 4;
    const float* src;
    bf16* dst;
    if (i < 4194304) {
        src = hs + i; dst = hsb + i;
    } else if (i < 7340032) {
        int off = i - 4194304;
        int which = off >> 20;           // 0=Wq 1=Wk 2=Wv
        int within = off & 1048575;
        src = (which == 0 ? Wq : which == 1 ? Wk : Wv) + within;
        dst = wqkv + off;
    } else {
        int off = i - 7340032;
        src = Wo + off; dst = wob + off;
    }
    float4 v = *(const float4*)src;
    bf16x4 o = { (bf16)v.x, (bf16)v.y, (bf16)v.z, (bf16)v.w };
    *(bf16x4*)dst = o;
}

// ---------------------------------------------------------------------------
// Kernel 2: QKV projection. (R12 structure + XCD-chunked block swizzle:
// 768 blocks -> 96/XCD contiguous; bijective since 768%8==0.)
// ---------------------------------------------------------------------------
__global__ __launch_bounds__(256, 3) void gemm_bt(
    const bf16* __restrict__ A, const bf16* __restrict__ Bm,
    const float* __restrict__ b0, const float* __restrict__ b1,
    const float* __restrict__ b2,
    bf16* __restrict__ Qo, bf16* __restrict__ Ko, bf16* __restrict__ Vt)
{
    const int K = 1024;
    __shared__ __attribute__((aligned(16))) bf16 sA[128 * 64];   // 16KB
    __shared__ __attribute__((aligned(16))) bf16 sB[128 * 64];   // 16KB

    int tid = threadIdx.x;
    int wave = tid >> 6, lane = tid & 63;
    int quad = lane >> 4, l16 = lane & 15;
    // XCD-chunked swizzle (T1): orig%8 ~ XCD id; each XCD gets a contiguous
    // logical chunk. lid = ny*32 + mx.
    int orig = blockIdx.y * 32 + blockIdx.x;
    int lid = (orig & 7) * 96 + (orig >> 3);
    int m0 = (lid & 31) * 128;
    int n0 = (lid >> 5) * 128;
    int wm = (wave & 1) * 64, wn = (wave >> 1) * 64;
    int fs = l16 & 7;                   // read-side swizzle key (row&7 == l16&7)

    f32x4 acc[4][4];
#pragma unroll
    for (int i = 0; i < 4; i++)
#pragma unroll
        for (int j = 0; j < 4; j++) acc[i][j] = (f32x4){0.f, 0.f, 0.f, 0.f};

    for (int k0 = 0; k0 < K; k0 += 64) {
#pragma unroll
        for (int i = 0; i < 4; i++) {
            int c = tid + i * 256;          // 0..1023, 16B each
            int row = c >> 3;               // 8 chunks per 64-elem row
            int kc = ((c & 7) ^ (row & 7)) * 8;   // swizzled source group
            gld_lds16(A + (size_t)(m0 + row) * K + k0 + kc, &sA[c * 8]);
            gld_lds16(Bm + (size_t)(n0 + row) * K + k0 + kc, &sB[c * 8]);
        }
        WAIT_VMCNT0();          // async LDS writes landed before barrier
        __syncthreads();

#pragma unroll
        for (int kp = 0; kp < 2; kp++) {     // two 32-col k-windows
            bf16x8 af[4], bfr[4];
#pragma unroll
            for (int i = 0; i < 4; i++)
                af[i] = *(const bf16x8*)&sA[(wm + i * 16 + l16) * 64 + (((kp * 4 + quad) ^ fs) * 8)];
#pragma unroll
            for (int j = 0; j < 4; j++)
                bfr[j] = *(const bf16x8*)&sB[(wn + j * 16 + l16) * 64 + (((kp * 4 + quad) ^ fs) * 8)];
#pragma unroll
            for (int i = 0; i < 4; i++)
#pragma unroll
                for (int j = 0; j < 4; j++)
                    acc[i][j] = __builtin_amdgcn_mfma_f32_16x16x32_bf16(
                        af[i], bfr[j], acc[i][j], 0, 0, 0);
        }
        __syncthreads();
    }

    // C/D layout: col = lane&15, row = quad*4 + reg  (m89/m91 verified)
    const float QSCALE = 0.125f * 1.44269504088896340736f;  // 1/sqrt(64)*log2(e)
#pragma unroll
    for (int j = 0; j < 4; j++) {
        int n = n0 + wn + j * 16 + l16;
        int region = n >> 10;            // block-uniform (n0 128-aligned)
        int nn = n & 1023;
        int h = nn >> 6, d = nn & 63;
        float bias = (region == 0 ? b0 : region == 1 ? b1 : b2)[nn];
#pragma unroll
        for (int i = 0; i < 4; i++) {
            int mb = m0 + wm + i * 16 + quad * 4;     // 4-aligned, no 2048-cross
            int b = mb >> 11, s = mb & 2047;
            int bh = b * H_ + h;
            if (region == 2) {
                // packed V^T store: 4 consecutive s at fixed d (b64)
                bf16x4 pk = { f2bf(acc[i][j][0] + bias), f2bf(acc[i][j][1] + bias),
                              f2bf(acc[i][j][2] + bias), f2bf(acc[i][j][3] + bias) };
                *(bf16x4*)&Vt[((size_t)bh * DH_ + d) * S_ + s] = pk;
            } else {
#pragma unroll
                for (int r = 0; r < 4; r++) {
                    float v = acc[i][j][r] + bias;
                    if (region == 0)
                        Qo[((size_t)bh * S_ + s + r) * DH_ + d] = f2bf(v * QSCALE);
                    else
                        Ko[((size_t)bh * S_ + s + r) * DH_ + d] = f2bf(v);
                }
            }
        }
    }
}

// ---------------------------------------------------------------------------
// Kernel 4: out = attn @ Wo^T + bo. 128m x 64n tile, BK=64.
// (R12 structure + XCD-chunked swizzle, 512 blocks -> 64/XCD.)
// ---------------------------------------------------------------------------
__global__ __launch_bounds__(256, 2) void gemm_out(
    const bf16* __restrict__ A, const bf16* __restrict__ Bm,
    const float* __restrict__ bias0, float* __restrict__ Co)
{
    const int K = 1024;
    __shared__ __attribute__((aligned(16))) bf16 sA[128 * 64];   // 16KB
    __shared__ __attribute__((aligned(16))) bf16 sB[64 * 64];    // 8KB

    int tid = threadIdx.x;
    int wave = tid >> 6, lane = tid & 63;
    int quad = lane >> 4, l16 = lane & 15;
    int orig = blockIdx.y * 32 + blockIdx.x;
    int lid = (orig & 7) * 64 + (orig >> 3);
    int m0 = (lid & 31) * 128;
    int n0 = (lid >> 5) * 64;
    int wm = (wave & 1) * 64, wn = (wave >> 1) * 32;
    int fs = l16 & 7;

    f32x4 acc[4][2];
#pragma unroll
    for (int i = 0; i < 4; i++)
#pragma unroll
        for (int j = 0; j < 2; j++) acc[i][j] = (f32x4){0.f, 0.f, 0.f, 0.f};

    for (int k0 = 0; k0 < K; k0 += 64) {
#pragma unroll
        for (int i = 0; i < 4; i++) {        // A: 1024 chunks
            int c = tid + i * 256;
            int row = c >> 3;
            int kc = ((c & 7) ^ (row & 7)) * 8;
            gld_lds16(A + (size_t)(m0 + row) * K + k0 + kc, &sA[c * 8]);
        }
#pragma unroll
        for (int i = 0; i < 2; i++) {        // B: 512 chunks
            int c = tid + i * 256;
            int row = c >> 3;
            int kc = ((c & 7) ^ (row & 7)) * 8;
            gld_lds16(Bm + (size_t)(n0 + row) * K + k0 + kc, &sB[c * 8]);
        }
        WAIT_VMCNT0();
        __syncthreads();

#pragma unroll
        for (int kp = 0; kp < 2; kp++) {
            bf16x8 af[4], bfr[2];
#pragma unroll
            for (int i = 0; i < 4; i++)
                af[i] = *(const bf16x8*)&sA[(wm + i * 16 + l16) * 64 + (((kp * 4 + quad) ^ fs) * 8)];
#pragma unroll
            for (int j = 0; j < 2; j++)
                bfr[j] = *(const bf16x8*)&sB[(wn + j * 16 + l16) * 64 + (((kp * 4 + quad) ^ fs) * 8)];
#pragma unroll
            for (int i = 0; i < 4; i++)
#pragma unroll
                for (int j = 0; j < 2; j++)
                    acc[i][j] = __builtin_amdgcn_mfma_f32_16x16x32_bf16(
                        af[i], bfr[j], acc[i][j], 0, 0, 0);
        }
        __syncthreads();
    }

#pragma unroll
    for (int j = 0; j < 2; j++) {
        int n = n0 + wn + j * 16 + l16;
        float bias = bias0[n];
#pragma unroll
        for (int i = 0; i < 4; i++)
#pragma unroll
            for (int r = 0; r < 4; r++) {
                int m = m0 + wm + i * 16 + quad * 4 + r;
                Co[(size_t)m * D_ + n] = acc[i][j][r] + bias;
            }
    }
}

// ---------------------------------------------------------------------------
// Kernel 3 (R19): flash attention = R15's verified loop BYTE-IDENTICAL
// (no setprio anywhere — banned per R16/R17/R18 isolation matrix) + ONLY the
// XCD-chunked block swizzle (bijective index remap; each XCD gets 4
// consecutive heads -> 2MB K/V working set, L2-resident).
// ---------------------------------------------------------------------------
__global__ __launch_bounds__(256, 4) void attn_kernel(
    const bf16* __restrict__ Q, const bf16* __restrict__ Kg,
    const bf16* __restrict__ Vt, const int* __restrict__ mask,
    bf16* __restrict__ Og)
{
    __shared__ __attribute__((aligned(16))) bf16 sK[128 * 64];        // [key][dh] 16KB
    __shared__ __attribute__((aligned(16))) bf16 sV[64 * 128];        // [d][key] 16KB
    __shared__ __attribute__((aligned(16))) unsigned short sMadd[S_]; // 4KB

    int tid = threadIdx.x;
    int wave = tid >> 6, lane = tid & 63;
    int quad = lane >> 4, l16 = lane & 15;
    // XCD-chunked swizzle: lid = bh*32 + qtile; each XCD gets 128 consecutive
    // lids = 4 full heads. 1024%8==0 -> bijective.
    int orig = blockIdx.y * 32 + blockIdx.x;
    int lid = (orig & 7) * 128 + (orig >> 3);
    int bh = lid >> 5;
    int q0 = (lid & 31) * 64;
    int b = bh >> 4;
    int f8 = l16 & 7;                          // sK read swizzle key
    int qh = wave & 1;                         // q-half (0/1), 32 q each
    int kh = wave >> 1;                        // key-half (0/1), 64 keys/iter each

    const bf16* Qb = Q + (size_t)bh * S_ * DH_;
    const bf16* Kb = Kg + (size_t)bh * S_ * DH_;
    const bf16* Vb = Vt + (size_t)bh * DH_ * S_;

    // expand mask row once per block: 1 -> 0x0000 (0.0f), 0 -> 0xF149 (-9.96e29)
    // 2048 entries / 256 threads = 8 each; published by the first loop barrier.
    {
        int base = b * S_ + tid * 8;
        int4 m0 = *(const int4*)&mask[base];
        int4 m1 = *(const int4*)&mask[base + 4];
        u16x4 e0 = { (unsigned short)(m0.x ? 0 : 0xF149),
                     (unsigned short)(m0.y ? 0 : 0xF149),
                     (unsigned short)(m0.z ? 0 : 0xF149),
                     (unsigned short)(m0.w ? 0 : 0xF149) };
        u16x4 e1 = { (unsigned short)(m1.x ? 0 : 0xF149),
                     (unsigned short)(m1.y ? 0 : 0xF149),
                     (unsigned short)(m1.z ? 0 : 0xF149),
                     (unsigned short)(m1.w ? 0 : 0xF149) };
        *(u16x4*)&sMadd[tid * 8] = e0;
        *(u16x4*)&sMadd[tid * 8 + 4] = e1;
    }

    // Q fragments for 2 q-tiles (B-operand; layout n=lane&15, k=quad*8+j)
    bf16x8 aq[2][2];
#pragma unroll
    for (int qt = 0; qt < 2; qt++) {
        int qrow = q0 + qh * 32 + qt * 16 + l16;
        aq[qt][0] = *(const bf16x8*)&Qb[(size_t)qrow * DH_ + quad * 8];
        aq[qt][1] = *(const bf16x8*)&Qb[(size_t)qrow * DH_ + 32 + quad * 8];
    }

    // ones B-fragment for row-sum MFMA
    const bf16 oneb = __builtin_bit_cast(bf16, (unsigned short)0x3F80);
    const bf16x8 ones = { oneb, oneb, oneb, oneb, oneb, oneb, oneb, oneb };

    f32x4 o[2][4];                       // o[qt][dt], C row=q, col=d
    f32x4 osum[2];                       // row-sums of P, C row=q (col dup'd)
#pragma unroll
    for (int i = 0; i < 2; i++) {
#pragma unroll
        for (int j = 0; j < 4; j++) o[i][j] = (f32x4){0.f, 0.f, 0.f, 0.f};
        osum[i] = (f32x4){0.f, 0.f, 0.f, 0.f};
    }

    for (int kt = 0; kt < S_; kt += 128) {
        // stage K[128k][64dh] + V^T[64d][128k]; source-col swizzled so the
        // lane-contiguous DMA dest gives conflict-free fragment reads.
#pragma unroll
        for (int i = 0; i < 8; i++) {
            int c = tid + i * 256;            // 0..2047
            if (c < 1024) {                   // K chunk: row=c>>3, group=c&7
                int row = c >> 3;
                int g = (c & 7) ^ (row & 7);
                gld_lds16(&Kb[(size_t)(kt + row) * DH_ + g * 8], &sK[c * 8]);
            } else {                          // V chunk: row=(c-1024)>>4, group=&15
                int cv = c - 1024;
                int row = cv >> 4;
                int g = (cv & 15) ^ (row & 15);
                gld_lds16(&Vb[(size_t)row * S_ + kt + g * 8], &sV[cv * 8]);
            }
        }
        WAIT_VMCNT0();
        __syncthreads();

#pragma unroll
        for (int pass = 0; pass < 2; pass++) {   // 32 keys per pass
            // --- S^T = K @ Q^T, P = exp2(S + maskadd), kept in registers ---
            unsigned w01[2][2], w23[2][2];       // [qt][mtl]: keys q'*4+{0,1}/{2,3}
#pragma unroll
            for (int mtl = 0; mtl < 2; mtl++) {
                int keyrow = kh * 64 + pass * 32 + mtl * 16;   // wave-local tile base
                bf16x8 ak0 = *(const bf16x8*)&sK[(keyrow + l16) * 64 + ((quad ^ f8) * 8)];
                bf16x8 ak1 = *(const bf16x8*)&sK[(keyrow + l16) * 64 + (((quad + 4) ^ f8) * 8)];
                u16x4 mm = *(const u16x4*)&sMadd[kt + keyrow + quad * 4];
                // mask-add as MFMA C-init (per key == per C row)
                f32x4 cinit;
                cinit[0] = __builtin_bit_cast(float, (unsigned)mm.x << 16);
                cinit[1] = __builtin_bit_cast(float, (unsigned)mm.y << 16);
                cinit[2] = __builtin_bit_cast(float, (unsigned)mm.z << 16);
                cinit[3] = __builtin_bit_cast(float, (unsigned)mm.w << 16);
#pragma unroll
                for (int qt = 0; qt < 2; qt++) {
                    f32x4 c = cinit;
                    c = __builtin_amdgcn_mfma_f32_16x16x32_bf16(ak0, aq[qt][0], c, 0, 0, 0);
                    c = __builtin_amdgcn_mfma_f32_16x16x32_bf16(ak1, aq[qt][1], c, 0, 0, 0);
                    float p0 = __builtin_amdgcn_exp2f(c[0]);
                    float p1 = __builtin_amdgcn_exp2f(c[1]);
                    float p2 = __builtin_amdgcn_exp2f(c[2]);
                    float p3 = __builtin_amdgcn_exp2f(c[3]);
                    w01[qt][mtl] = cvtpk(p0, p1);
                    w23[qt][mtl] = cvtpk(p2, p3);
                }
            }

            // --- in-register remap (R13-verified): -> PV A-frag words ---
            bf16x8 ap[2];
#pragma unroll
            for (int qt = 0; qt < 2; qt++) {
                unsigned r0 = w01[qt][0], r2 = w01[qt][1];     // j=0 pair
                pl32swap(r0, r2); pl16swap(r0, r2);            // -> word0, word2
                unsigned r1 = w23[qt][0], r3 = w23[qt][1];     // j=1 pair
                pl32swap(r1, r3); pl16swap(r1, r3);            // -> word1, word3
                union { unsigned u[4]; bf16x8 v; } U;
                U.u[0] = r0; U.u[1] = r1; U.u[2] = r2; U.u[3] = r3;
                ap[qt] = U.v;
                // row-sums: osum[qt] += P @ ones  (replaces scalar psum adds)
                osum[qt] = __builtin_amdgcn_mfma_f32_16x16x32_bf16(ap[qt], ones, osum[qt], 0, 0, 0);
            }

            // --- O += P @ V (A=P[q][k32] in regs, B=V^T[d][k32]) ---
#pragma unroll
            for (int dt = 0; dt < 4; dt++) {
                int g = (kh * 8 + pass * 4 + quad) ^ l16;      // sV group slot
                bf16x8 bv = *(const bf16x8*)&sV[(dt * 16 + l16) * 128 + g * 8];
#pragma unroll
                for (int qt = 0; qt < 2; qt++)
                    o[qt][dt] = __builtin_amdgcn_mfma_f32_16x16x32_bf16(ap[qt], bv, o[qt][dt], 0, 0, 0);
            }
        }
        __syncthreads();   // all fragment reads done before next staging
    }

    // cross-wave reduction: waves 2,3 (key-half 1) hand partials (o + osum)
    // to waves 0,1. Slots 0..7 = o[qt][dt], slots 8..9 = osum[qt].
    float* sRed = (wave == 2) ? (float*)sK : (float*)sV;   // 16KB each, 10KB used
    if (wave >= 2) {
#pragma unroll
        for (int qt = 0; qt < 2; qt++) {
#pragma unroll
            for (int dt = 0; dt < 4; dt++)
                *(f32x4*)&sRed[((qt * 4 + dt) * 64 + lane) * 4] = o[qt][dt];
            *(f32x4*)&sRed[((8 + qt) * 64 + lane) * 4] = osum[qt];
        }
    }
    __syncthreads();
    if (wave < 2) {
        float* src = (wave == 0) ? (float*)sK : (float*)sV;
#pragma unroll
        for (int qt = 0; qt < 2; qt++) {
#pragma unroll
            for (int dt = 0; dt < 4; dt++)
                o[qt][dt] += *(const f32x4*)&src[((qt * 4 + dt) * 64 + lane) * 4];
            osum[qt] += *(const f32x4*)&src[((8 + qt) * 64 + lane) * 4];
        }
        int h = bh & 15;
#pragma unroll
        for (int qt = 0; qt < 2; qt++) {
            // osum reg r holds full psum for q = qt*16 + quad*4 + r (cols dup)
            float rcp[4] = { 1.f / osum[qt][0], 1.f / osum[qt][1],
                             1.f / osum[qt][2], 1.f / osum[qt][3] };
#pragma unroll
            for (int r = 0; r < 4; r++) {
                int s = q0 + wave * 32 + qt * 16 + quad * 4 + r;   // qh==wave here
#pragma unroll
                for (int dt = 0; dt < 4; dt++) {
                    int d = dt * 16 + l16;
                    Og[((size_t)(b * S_ + s)) * D_ + h * 64 + d] = f2bf(o[qt][dt][r] * rcp[r]);
                }
            }
        }
    }
}

// ---------------------------------------------------------------------------
extern "C" void kernel_launch(void* const* d_in, const int* in_sizes, int n_in,
                              void* d_out, int out_size, void* d_ws, size_t ws_size,
                              hipStream_t stream) {
    const float* hs = (const float*)d_in[0];
    const int* mask = (const int*)d_in[1];
    const float* Wq = (const float*)d_in[2];
    const float* bq = (const float*)d_in[3];
    const float* Wk = (const float*)d_in[4];
    const float* bk = (const float*)d_in[5];
    const float* Wv = (const float*)d_in[6];
    const float* bv = (const float*)d_in[7];
    const float* Wo = (const float*)d_in[8];
    const float* bo = (const float*)d_in[9];
    float* out = (float*)d_out;

    char* ws = (char*)d_ws;
    bf16* hsb  = (bf16*)(ws);                          // 8 MB (4096x1024)
    bf16* wqkv = (bf16*)(ws + ((size_t)8 << 20));      // 6 MB (3072x1024)
    bf16* wob  = (bf16*)(ws + ((size_t)14 << 20));     // 2 MB (1024x1024)
    bf16* Qw   = (bf16*)(ws + ((size_t)16 << 20));     // 8 MB (b,h,s,d)
    bf16* Kw   = (bf16*)(ws + ((size_t)24 << 20));     // 8 MB (b,h,s,d)
    bf16* Vtw  = (bf16*)(ws + ((size_t)32 << 20));     // 8 MB (b,h,d,s)
    bf16* attn = (bf16*)(ws + ((size_t)40 << 20));     // 8 MB (b,s,h*64+d)

    cvt_kernel<<<8192, 256, 0, stream>>>(hs, Wq, Wk, Wv, Wo, hsb, wqkv, wob);
    gemm_bt<<<dim3(32, 24), 256, 0, stream>>>(hsb, wqkv, bq, bk, bv,
                                              Qw, Kw, Vtw);
    attn_kernel<<<dim3(32, 32), 256, 0, stream>>>(Qw, Kw, Vtw, mask, attn);
    gemm_out<<<dim3(32, 16), 256, 0, stream>>>(attn, wob, bo, out);
}

// Round 9
// 186.323 us; speedup vs baseline: 1.0105x; 1.0105x over previous
//
#include <hip/hip_runtime.h>
#include <hip/hip_bf16.h>

typedef __bf16 bf16;
typedef __bf16 bf16x4 __attribute__((ext_vector_type(4)));
typedef __bf16 bf16x8 __attribute__((ext_vector_type(8)));
typedef float f32x4 __attribute__((ext_vector_type(4)));
typedef unsigned short u16x4 __attribute__((ext_vector_type(4)));

#define B_ 2
#define S_ 2048
#define H_ 16
#define DH_ 64
#define D_ 1024

// Ordering notes (R2 post-mortem): global_load_lds retires on vmcnt, ds_* on
// lgkmcnt. Two edges MUST be explicit:
//   (1) vmcnt(0) before the barrier that publishes freshly staged LDS tiles.
//   (2) lgkmcnt(0) between a wave's own ds_write and its ds_read of the same
//       bytes.
// R6+R8+R14: explicit double-buffering regressed three times.
// R16/R17/R18/R19: __builtin_amdgcn_s_setprio corrupts output
// nondeterministically here — BANNED.
// R20: 8-wave attn restructure corrupted despite audit-clean source (second
// audit-clean failure after R16). ATTN LOOP+EPILOGUE SHAPE IS FROZEN at the
// R15/R19-verified form — only provably-orthogonal changes allowed.
#define WAIT_VMCNT0() asm volatile("s_waitcnt vmcnt(0)" ::: "memory")
#define WAIT_LGKM0()  asm volatile("s_waitcnt lgkmcnt(0)" ::: "memory")

// async global->LDS, 16B per lane; LDS dest is wave-uniform base + lane*16
__device__ __forceinline__ void gld_lds16(const bf16* g, bf16* l) {
    __builtin_amdgcn_global_load_lds(
        (__attribute__((address_space(1))) void*)g,
        (__attribute__((address_space(3))) void*)l, 16, 0, 0);
}

// fast RNE float->bf16, no NaN/denorm path (inputs are finite, well-scaled)
__device__ __forceinline__ bf16 f2bf(float x) {
    union { float f; unsigned u; } v; v.f = x;
    unsigned short h = (unsigned short)((v.u + 0x7FFF + ((v.u >> 16) & 1)) >> 16);
    return __builtin_bit_cast(bf16, h);
}

// packed f32x2 -> bf16x2 (RNE), single VALU op (no builtin on gfx950, m240)
__device__ __forceinline__ unsigned cvtpk(float lo, float hi) {
    unsigned r;
    asm("v_cvt_pk_bf16_f32 %0, %1, %2" : "=v"(r) : "v"(lo), "v"(hi));
    return r;
}

// v_permlane32_swap_b32: a.row1 <-> b.row0  =>  a'={a.lo32,b.lo32}, b'={a.hi32,b.hi32}
__device__ __forceinline__ void pl32swap(unsigned &a, unsigned &b) {
    asm("v_permlane32_swap_b32 %0, %1" : "+v"(a), "+v"(b));
}
// v_permlane16_swap_b32: odd 16-rows of a <-> even 16-rows of b
__device__ __forceinline__ void pl16swap(unsigned &a, unsigned &b) {
    asm("v_permlane16_swap_b32 %0, %1" : "+v"(a), "+v"(b));
}

// ---------------------------------------------------------------------------
// Kernel 1 (R21): fp32 -> bf16 conversion/packing, 8 elems/thread (2x float4
// load -> one 16B bf16x8 store). All segment boundaries are multiples of 8:
// hs ends 4194304, W internal boundaries at 1048576 steps, Wo starts 7340032.
// ---------------------------------------------------------------------------
__global__ __launch_bounds__(256) void cvt_kernel(
    const float* __restrict__ hs,
    const float* __restrict__ Wq, const float* __restrict__ Wk,
    const float* __restrict__ Wv, const float* __restrict__ Wo,
    bf16* __restrict__ hsb, bf16* __restrict__ wqkv, bf16* __restrict__ wob)
{
    int i = (blockIdx.x * 256 + threadIdx.x) * 8;
    const float* src;
    bf16* dst;
    if (i < 4194304) {
        src = hs + i; dst = hsb + i;
    } else if (i < 7340032) {
        int off = i - 4194304;
        int which = off >> 20;           // 0=Wq 1=Wk 2=Wv
        int within = off & 1048575;
        src = (which == 0 ? Wq : which == 1 ? Wk : Wv) + within;
        dst = wqkv + off;
    } else {
        int off = i - 7340032;
        src = Wo + off; dst = wob + off;
    }
    float4 v0 = *(const float4*)src;
    float4 v1 = *(const float4*)(src + 4);
    bf16x8 o = { (bf16)v0.x, (bf16)v0.y, (bf16)v0.z, (bf16)v0.w,
                 (bf16)v1.x, (bf16)v1.y, (bf16)v1.z, (bf16)v1.w };
    *(bf16x8*)dst = o;
}

// ---------------------------------------------------------------------------
// Kernel 2: QKV projection. (R19-verified: R12 structure + XCD-chunked
// block swizzle; 768 blocks -> 96/XCD contiguous, bijective.) UNCHANGED.
// ---------------------------------------------------------------------------
__global__ __launch_bounds__(256, 3) void gemm_bt(
    const bf16* __restrict__ A, const bf16* __restrict__ Bm,
    const float* __restrict__ b0, const float* __restrict__ b1,
    const float* __restrict__ b2,
    bf16* __restrict__ Qo, bf16* __restrict__ Ko, bf16* __restrict__ Vt)
{
    const int K = 1024;
    __shared__ __attribute__((aligned(16))) bf16 sA[128 * 64];   // 16KB
    __shared__ __attribute__((aligned(16))) bf16 sB[128 * 64];   // 16KB

    int tid = threadIdx.x;
    int wave = tid >> 6, lane = tid & 63;
    int quad = lane >> 4, l16 = lane & 15;
    int orig = blockIdx.y * 32 + blockIdx.x;
    int lid = (orig & 7) * 96 + (orig >> 3);
    int m0 = (lid & 31) * 128;
    int n0 = (lid >> 5) * 128;
    int wm = (wave & 1) * 64, wn = (wave >> 1) * 64;
    int fs = l16 & 7;                   // read-side swizzle key (row&7 == l16&7)

    f32x4 acc[4][4];
#pragma unroll
    for (int i = 0; i < 4; i++)
#pragma unroll
        for (int j = 0; j < 4; j++) acc[i][j] = (f32x4){0.f, 0.f, 0.f, 0.f};

    for (int k0 = 0; k0 < K; k0 += 64) {
#pragma unroll
        for (int i = 0; i < 4; i++) {
            int c = tid + i * 256;          // 0..1023, 16B each
            int row = c >> 3;               // 8 chunks per 64-elem row
            int kc = ((c & 7) ^ (row & 7)) * 8;   // swizzled source group
            gld_lds16(A + (size_t)(m0 + row) * K + k0 + kc, &sA[c * 8]);
            gld_lds16(Bm + (size_t)(n0 + row) * K + k0 + kc, &sB[c * 8]);
        }
        WAIT_VMCNT0();          // async LDS writes landed before barrier
        __syncthreads();

#pragma unroll
        for (int kp = 0; kp < 2; kp++) {     // two 32-col k-windows
            bf16x8 af[4], bfr[4];
#pragma unroll
            for (int i = 0; i < 4; i++)
                af[i] = *(const bf16x8*)&sA[(wm + i * 16 + l16) * 64 + (((kp * 4 + quad) ^ fs) * 8)];
#pragma unroll
            for (int j = 0; j < 4; j++)
                bfr[j] = *(const bf16x8*)&sB[(wn + j * 16 + l16) * 64 + (((kp * 4 + quad) ^ fs) * 8)];
#pragma unroll
            for (int i = 0; i < 4; i++)
#pragma unroll
                for (int j = 0; j < 4; j++)
                    acc[i][j] = __builtin_amdgcn_mfma_f32_16x16x32_bf16(
                        af[i], bfr[j], acc[i][j], 0, 0, 0);
        }
        __syncthreads();
    }

    // C/D layout: col = lane&15, row = quad*4 + reg  (m89/m91 verified)
    const float QSCALE = 0.125f * 1.44269504088896340736f;  // 1/sqrt(64)*log2(e)
#pragma unroll
    for (int j = 0; j < 4; j++) {
        int n = n0 + wn + j * 16 + l16;
        int region = n >> 10;            // block-uniform (n0 128-aligned)
        int nn = n & 1023;
        int h = nn >> 6, d = nn & 63;
        float bias = (region == 0 ? b0 : region == 1 ? b1 : b2)[nn];
#pragma unroll
        for (int i = 0; i < 4; i++) {
            int mb = m0 + wm + i * 16 + quad * 4;     // 4-aligned, no 2048-cross
            int b = mb >> 11, s = mb & 2047;
            int bh = b * H_ + h;
            if (region == 2) {
                // packed V^T store: 4 consecutive s at fixed d (b64)
                bf16x4 pk = { f2bf(acc[i][j][0] + bias), f2bf(acc[i][j][1] + bias),
                              f2bf(acc[i][j][2] + bias), f2bf(acc[i][j][3] + bias) };
                *(bf16x4*)&Vt[((size_t)bh * DH_ + d) * S_ + s] = pk;
            } else {
#pragma unroll
                for (int r = 0; r < 4; r++) {
                    float v = acc[i][j][r] + bias;
                    if (region == 0)
                        Qo[((size_t)bh * S_ + s + r) * DH_ + d] = f2bf(v * QSCALE);
                    else
                        Ko[((size_t)bh * S_ + s + r) * DH_ + d] = f2bf(v);
                }
            }
        }
    }
}

// ---------------------------------------------------------------------------
// Kernel 4 (R21): out = attn @ Wo^T + bo. 128m x 64n block, BK=64 — now with
// 8 WAVES (512 threads): same 512-block grid (2/CU) but 16 waves/CU (was 8,
// the 25%-occupancy latency-exposed regime that cost attn 40% pre-R13).
// Waves as 4m x 2n -> each 32m x 32n, acc[2][2]; per-block staging bytes and
// total MFMA count unchanged; per-thread staging 6 -> 3 chunks.
// Index algebra is the verified pattern with wm=(wave&3)*32, wn=(wave>>2)*32.
// ---------------------------------------------------------------------------
__global__ __launch_bounds__(512, 4) void gemm_out(
    const bf16* __restrict__ A, const bf16* __restrict__ Bm,
    const float* __restrict__ bias0, float* __restrict__ Co)
{
    const int K = 1024;
    __shared__ __attribute__((aligned(16))) bf16 sA[128 * 64];   // 16KB
    __shared__ __attribute__((aligned(16))) bf16 sB[64 * 64];    // 8KB

    int tid = threadIdx.x;
    int wave = tid >> 6, lane = tid & 63;
    int quad = lane >> 4, l16 = lane & 15;
    int orig = blockIdx.y * 32 + blockIdx.x;
    int lid = (orig & 7) * 64 + (orig >> 3);
    int m0 = (lid & 31) * 128;
    int n0 = (lid >> 5) * 64;
    int wm = (wave & 3) * 32, wn = (wave >> 2) * 32;
    int fs = l16 & 7;

    f32x4 acc[2][2];
#pragma unroll
    for (int i = 0; i < 2; i++)
#pragma unroll
        for (int j = 0; j < 2; j++) acc[i][j] = (f32x4){0.f, 0.f, 0.f, 0.f};

    for (int k0 = 0; k0 < K; k0 += 64) {
#pragma unroll
        for (int i = 0; i < 2; i++) {        // A: 1024 chunks, 2/thread
            int c = tid + i * 512;
            int row = c >> 3;
            int kc = ((c & 7) ^ (row & 7)) * 8;
            gld_lds16(A + (size_t)(m0 + row) * K + k0 + kc, &sA[c * 8]);
        }
        {                                    // B: 512 chunks, 1/thread
            int c = tid;
            int row = c >> 3;                // rows 0..63
            int kc = ((c & 7) ^ (row & 7)) * 8;
            gld_lds16(Bm + (size_t)(n0 + row) * K + k0 + kc, &sB[c * 8]);
        }
        WAIT_VMCNT0();
        __syncthreads();

#pragma unroll
        for (int kp = 0; kp < 2; kp++) {
            bf16x8 af[2], bfr[2];
#pragma unroll
            for (int i = 0; i < 2; i++)
                af[i] = *(const bf16x8*)&sA[(wm + i * 16 + l16) * 64 + (((kp * 4 + quad) ^ fs) * 8)];
#pragma unroll
            for (int j = 0; j < 2; j++)
                bfr[j] = *(const bf16x8*)&sB[(wn + j * 16 + l16) * 64 + (((kp * 4 + quad) ^ fs) * 8)];
#pragma unroll
            for (int i = 0; i < 2; i++)
#pragma unroll
                for (int j = 0; j < 2; j++)
                    acc[i][j] = __builtin_amdgcn_mfma_f32_16x16x32_bf16(
                        af[i], bfr[j], acc[i][j], 0, 0, 0);
        }
        __syncthreads();
    }

#pragma unroll
    for (int j = 0; j < 2; j++) {
        int n = n0 + wn + j * 16 + l16;
        float bias = bias0[n];
#pragma unroll
        for (int i = 0; i < 2; i++)
#pragma unroll
            for (int r = 0; r < 4; r++) {
                int m = m0 + wm + i * 16 + quad * 4 + r;
                Co[(size_t)m * D_ + n] = acc[i][j][r] + bias;
            }
    }
}

// ---------------------------------------------------------------------------
// Kernel 3: flash attention — R19 BYTE-IDENTICAL (verified passing, 50.8us,
// FETCH 12.4MB). Loop+epilogue shape FROZEN per R16/R20 post-mortems.
// ---------------------------------------------------------------------------
__global__ __launch_bounds__(256, 4) void attn_kernel(
    const bf16* __restrict__ Q, const bf16* __restrict__ Kg,
    const bf16* __restrict__ Vt, const int* __restrict__ mask,
    bf16* __restrict__ Og)
{
    __shared__ __attribute__((aligned(16))) bf16 sK[128 * 64];        // [key][dh] 16KB
    __shared__ __attribute__((aligned(16))) bf16 sV[64 * 128];        // [d][key] 16KB
    __shared__ __attribute__((aligned(16))) unsigned short sMadd[S_]; // 4KB

    int tid = threadIdx.x;
    int wave = tid >> 6, lane = tid & 63;
    int quad = lane >> 4, l16 = lane & 15;
    // XCD-chunked swizzle: lid = bh*32 + qtile; each XCD gets 128 consecutive
    // lids = 4 full heads. 1024%8==0 -> bijective.
    int orig = blockIdx.y * 32 + blockIdx.x;
    int lid = (orig & 7) * 128 + (orig >> 3);
    int bh = lid >> 5;
    int q0 = (lid & 31) * 64;
    int b = bh >> 4;
    int f8 = l16 & 7;                          // sK read swizzle key
    int qh = wave & 1;                         // q-half (0/1), 32 q each
    int kh = wave >> 1;                        // key-half (0/1), 64 keys/iter each

    const bf16* Qb = Q + (size_t)bh * S_ * DH_;
    const bf16* Kb = Kg + (size_t)bh * S_ * DH_;
    const bf16* Vb = Vt + (size_t)bh * DH_ * S_;

    // expand mask row once per block: 1 -> 0x0000 (0.0f), 0 -> 0xF149 (-9.96e29)
    // 2048 entries / 256 threads = 8 each; published by the first loop barrier.
    {
        int base = b * S_ + tid * 8;
        int4 m0 = *(const int4*)&mask[base];
        int4 m1 = *(const int4*)&mask[base + 4];
        u16x4 e0 = { (unsigned short)(m0.x ? 0 : 0xF149),
                     (unsigned short)(m0.y ? 0 : 0xF149),
                     (unsigned short)(m0.z ? 0 : 0xF149),
                     (unsigned short)(m0.w ? 0 : 0xF149) };
        u16x4 e1 = { (unsigned short)(m1.x ? 0 : 0xF149),
                     (unsigned short)(m1.y ? 0 : 0xF149),
                     (unsigned short)(m1.z ? 0 : 0xF149),
                     (unsigned short)(m1.w ? 0 : 0xF149) };
        *(u16x4*)&sMadd[tid * 8] = e0;
        *(u16x4*)&sMadd[tid * 8 + 4] = e1;
    }

    // Q fragments for 2 q-tiles (B-operand; layout n=lane&15, k=quad*8+j)
    bf16x8 aq[2][2];
#pragma unroll
    for (int qt = 0; qt < 2; qt++) {
        int qrow = q0 + qh * 32 + qt * 16 + l16;
        aq[qt][0] = *(const bf16x8*)&Qb[(size_t)qrow * DH_ + quad * 8];
        aq[qt][1] = *(const bf16x8*)&Qb[(size_t)qrow * DH_ + 32 + quad * 8];
    }

    // ones B-fragment for row-sum MFMA
    const bf16 oneb = __builtin_bit_cast(bf16, (unsigned short)0x3F80);
    const bf16x8 ones = { oneb, oneb, oneb, oneb, oneb, oneb, oneb, oneb };

    f32x4 o[2][4];                       // o[qt][dt], C row=q, col=d
    f32x4 osum[2];                       // row-sums of P, C row=q (col dup'd)
#pragma unroll
    for (int i = 0; i < 2; i++) {
#pragma unroll
        for (int j = 0; j < 4; j++) o[i][j] = (f32x4){0.f, 0.f, 0.f, 0.f};
        osum[i] = (f32x4){0.f, 0.f, 0.f, 0.f};
    }

    for (int kt = 0; kt < S_; kt += 128) {
        // stage K[128k][64dh] + V^T[64d][128k]; source-col swizzled so the
        // lane-contiguous DMA dest gives conflict-free fragment reads.
#pragma unroll
        for (int i = 0; i < 8; i++) {
            int c = tid + i * 256;            // 0..2047
            if (c < 1024) {                   // K chunk: row=c>>3, group=c&7
                int row = c >> 3;
                int g = (c & 7) ^ (row & 7);
                gld_lds16(&Kb[(size_t)(kt + row) * DH_ + g * 8], &sK[c * 8]);
            } else {                          // V chunk: row=(c-1024)>>4, group=&15
                int cv = c - 1024;
                int row = cv >> 4;
                int g = (cv & 15) ^ (row & 15);
                gld_lds16(&Vb[(size_t)row * S_ + kt + g * 8], &sV[cv * 8]);
            }
        }
        WAIT_VMCNT0();
        __syncthreads();

#pragma unroll
        for (int pass = 0; pass < 2; pass++) {   // 32 keys per pass
            // --- S^T = K @ Q^T, P = exp2(S + maskadd), kept in registers ---
            unsigned w01[2][2], w23[2][2];       // [qt][mtl]: keys q'*4+{0,1}/{2,3}
#pragma unroll
            for (int mtl = 0; mtl < 2; mtl++) {
                int keyrow = kh * 64 + pass * 32 + mtl * 16;   // wave-local tile base
                bf16x8 ak0 = *(const bf16x8*)&sK[(keyrow + l16) * 64 + ((quad ^ f8) * 8)];
                bf16x8 ak1 = *(const bf16x8*)&sK[(keyrow + l16) * 64 + (((quad + 4) ^ f8) * 8)];
                u16x4 mm = *(const u16x4*)&sMadd[kt + keyrow + quad * 4];
                // mask-add as MFMA C-init (per key == per C row)
                f32x4 cinit;
                cinit[0] = __builtin_bit_cast(float, (unsigned)mm.x << 16);
                cinit[1] = __builtin_bit_cast(float, (unsigned)mm.y << 16);
                cinit[2] = __builtin_bit_cast(float, (unsigned)mm.z << 16);
                cinit[3] = __builtin_bit_cast(float, (unsigned)mm.w << 16);
#pragma unroll
                for (int qt = 0; qt < 2; qt++) {
                    f32x4 c = cinit;
                    c = __builtin_amdgcn_mfma_f32_16x16x32_bf16(ak0, aq[qt][0], c, 0, 0, 0);
                    c = __builtin_amdgcn_mfma_f32_16x16x32_bf16(ak1, aq[qt][1], c, 0, 0, 0);
                    float p0 = __builtin_amdgcn_exp2f(c[0]);
                    float p1 = __builtin_amdgcn_exp2f(c[1]);
                    float p2 = __builtin_amdgcn_exp2f(c[2]);
                    float p3 = __builtin_amdgcn_exp2f(c[3]);
                    w01[qt][mtl] = cvtpk(p0, p1);
                    w23[qt][mtl] = cvtpk(p2, p3);
                }
            }

            // --- in-register remap (R13-verified): -> PV A-frag words ---
            bf16x8 ap[2];
#pragma unroll
            for (int qt = 0; qt < 2; qt++) {
                unsigned r0 = w01[qt][0], r2 = w01[qt][1];     // j=0 pair
                pl32swap(r0, r2); pl16swap(r0, r2);            // -> word0, word2
                unsigned r1 = w23[qt][0], r3 = w23[qt][1];     // j=1 pair
                pl32swap(r1, r3); pl16swap(r1, r3);            // -> word1, word3
                union { unsigned u[4]; bf16x8 v; } U;
                U.u[0] = r0; U.u[1] = r1; U.u[2] = r2; U.u[3] = r3;
                ap[qt] = U.v;
                // row-sums: osum[qt] += P @ ones  (replaces scalar psum adds)
                osum[qt] = __builtin_amdgcn_mfma_f32_16x16x32_bf16(ap[qt], ones, osum[qt], 0, 0, 0);
            }

            // --- O += P @ V (A=P[q][k32] in regs, B=V^T[d][k32]) ---
#pragma unroll
            for (int dt = 0; dt < 4; dt++) {
                int g = (kh * 8 + pass * 4 + quad) ^ l16;      // sV group slot
                bf16x8 bv = *(const bf16x8*)&sV[(dt * 16 + l16) * 128 + g * 8];
#pragma unroll
                for (int qt = 0; qt < 2; qt++)
                    o[qt][dt] = __builtin_amdgcn_mfma_f32_16x16x32_bf16(ap[qt], bv, o[qt][dt], 0, 0, 0);
            }
        }
        __syncthreads();   // all fragment reads done before next staging
    }

    // cross-wave reduction: waves 2,3 (key-half 1) hand partials (o + osum)
    // to waves 0,1. Slots 0..7 = o[qt][dt], slots 8..9 = osum[qt].
    float* sRed = (wave == 2) ? (float*)sK : (float*)sV;   // 16KB each, 10KB used
    if (wave >= 2) {
#pragma unroll
        for (int qt = 0; qt < 2; qt++) {
#pragma unroll
            for (int dt = 0; dt < 4; dt++)
                *(f32x4*)&sRed[((qt * 4 + dt) * 64 + lane) * 4] = o[qt][dt];
            *(f32x4*)&sRed[((8 + qt) * 64 + lane) * 4] = osum[qt];
        }
    }
    __syncthreads();
    if (wave < 2) {
        float* src = (wave == 0) ? (float*)sK : (float*)sV;
#pragma unroll
        for (int qt = 0; qt < 2; qt++) {
#pragma unroll
            for (int dt = 0; dt < 4; dt++)
                o[qt][dt] += *(const f32x4*)&src[((qt * 4 + dt) * 64 + lane) * 4];
            osum[qt] += *(const f32x4*)&src[((8 + qt) * 64 + lane) * 4];
        }
        int h = bh & 15;
#pragma unroll
        for (int qt = 0; qt < 2; qt++) {
            // osum reg r holds full psum for q = qt*16 + quad*4 + r (cols dup)
            float rcp[4] = { 1.f / osum[qt][0], 1.f / osum[qt][1],
                             1.f / osum[qt][2], 1.f / osum[qt][3] };
#pragma unroll
            for (int r = 0; r < 4; r++) {
                int s = q0 + wave * 32 + qt * 16 + quad * 4 + r;   // qh==wave here
#pragma unroll
                for (int dt = 0; dt < 4; dt++) {
                    int d = dt * 16 + l16;
                    Og[((size_t)(b * S_ + s)) * D_ + h * 64 + d] = f2bf(o[qt][dt][r] * rcp[r]);
                }
            }
        }
    }
}

// ---------------------------------------------------------------------------
extern "C" void kernel_launch(void* const* d_in, const int* in_sizes, int n_in,
                              void* d_out, int out_size, void* d_ws, size_t ws_size,
                              hipStream_t stream) {
    const float* hs = (const float*)d_in[0];
    const int* mask = (const int*)d_in[1];
    const float* Wq = (const float*)d_in[2];
    const float* bq = (const float*)d_in[3];
    const float* Wk = (const float*)d_in[4];
    const float* bk = (const float*)d_in[5];
    const float* Wv = (const float*)d_in[6];
    const float* bv = (const float*)d_in[7];
    const float* Wo = (const float*)d_in[8];
    const float* bo = (const float*)d_in[9];
    float* out = (float*)d_out;

    char* ws = (char*)d_ws;
    bf16* hsb  = (bf16*)(ws);                          // 8 MB (4096x1024)
    bf16* wqkv = (bf16*)(ws + ((size_t)8 << 20));      // 6 MB (3072x1024)
    bf16* wob  = (bf16*)(ws + ((size_t)14 << 20));     // 2 MB (1024x1024)
    bf16* Qw   = (bf16*)(ws + ((size_t)16 << 20));     // 8 MB (b,h,s,d)
    bf16* Kw   = (bf16*)(ws + ((size_t)24 << 20));     // 8 MB (b,h,s,d)
    bf16* Vtw  = (bf16*)(ws + ((size_t)32 << 20));     // 8 MB (b,h,d,s)
    bf16* attn = (bf16*)(ws + ((size_t)40 << 20));     // 8 MB (b,s,h*64+d)

    cvt_kernel<<<4096, 256, 0, stream>>>(hs, Wq, Wk, Wv, Wo, hsb, wqkv, wob);
    gemm_bt<<<dim3(32, 24), 256, 0, stream>>>(hsb, wqkv, bq, bk, bv,
                                              Qw, Kw, Vtw);
    attn_kernel<<<dim3(32, 32), 256, 0, stream>>>(Qw, Kw, Vtw, mask, attn);
    gemm_out<<<dim3(32, 16), 512, 0, stream>>>(attn, wob, bo, out);
}

// Round 10
// 184.197 us; speedup vs baseline: 1.0222x; 1.0115x over previous
//
#include <hip/hip_runtime.h>
#include <hip/hip_bf16.h>

typedef __bf16 bf16;
typedef __bf16 bf16x4 __attribute__((ext_vector_type(4)));
typedef __bf16 bf16x8 __attribute__((ext_vector_type(8)));
typedef float f32x4 __attribute__((ext_vector_type(4)));
typedef unsigned short u16x4 __attribute__((ext_vector_type(4)));

#define B_ 2
#define S_ 2048
#define H_ 16
#define DH_ 64
#define D_ 1024

// Ordering notes (R2 post-mortem): global_load_lds retires on vmcnt, ds_* on
// lgkmcnt. Two edges MUST be explicit:
//   (1) vmcnt(0) before the barrier that publishes freshly staged LDS tiles.
//   (2) lgkmcnt(0) between a wave's own ds_write and its ds_read of the same
//       bytes.
// R6+R8+R14: explicit double-buffering regressed three times.
// R16/R17/R18/R19: __builtin_amdgcn_s_setprio corrupts output
// nondeterministically here — BANNED.
// R20: 8-wave attn restructure corrupted despite audit-clean source. ATTN
// LOOP+EPILOGUE SHAPE IS FROZEN at the R15/R19-verified form.
// R21/R22: structural edits to the GEMM kernels (retile, index remaps) have
// passed — the corruption class is attn-specific.
#define WAIT_VMCNT0() asm volatile("s_waitcnt vmcnt(0)" ::: "memory")
#define WAIT_LGKM0()  asm volatile("s_waitcnt lgkmcnt(0)" ::: "memory")

// async global->LDS, 16B per lane; LDS dest is wave-uniform base + lane*16
__device__ __forceinline__ void gld_lds16(const bf16* g, bf16* l) {
    __builtin_amdgcn_global_load_lds(
        (__attribute__((address_space(1))) void*)g,
        (__attribute__((address_space(3))) void*)l, 16, 0, 0);
}

// fast RNE float->bf16, no NaN/denorm path (inputs are finite, well-scaled)
__device__ __forceinline__ bf16 f2bf(float x) {
    union { float f; unsigned u; } v; v.f = x;
    unsigned short h = (unsigned short)((v.u + 0x7FFF + ((v.u >> 16) & 1)) >> 16);
    return __builtin_bit_cast(bf16, h);
}

// packed f32x2 -> bf16x2 (RNE), single VALU op (no builtin on gfx950, m240)
__device__ __forceinline__ unsigned cvtpk(float lo, float hi) {
    unsigned r;
    asm("v_cvt_pk_bf16_f32 %0, %1, %2" : "=v"(r) : "v"(lo), "v"(hi));
    return r;
}

// v_permlane32_swap_b32: a.row1 <-> b.row0  =>  a'={a.lo32,b.lo32}, b'={a.hi32,b.hi32}
__device__ __forceinline__ void pl32swap(unsigned &a, unsigned &b) {
    asm("v_permlane32_swap_b32 %0, %1" : "+v"(a), "+v"(b));
}
// v_permlane16_swap_b32: odd 16-rows of a <-> even 16-rows of b
__device__ __forceinline__ void pl16swap(unsigned &a, unsigned &b) {
    asm("v_permlane16_swap_b32 %0, %1" : "+v"(a), "+v"(b));
}

// ---------------------------------------------------------------------------
// Kernel 1 (R21-verified): fp32 -> bf16, 8 elems/thread.
// ---------------------------------------------------------------------------
__global__ __launch_bounds__(256) void cvt_kernel(
    const float* __restrict__ hs,
    const float* __restrict__ Wq, const float* __restrict__ Wk,
    const float* __restrict__ Wv, const float* __restrict__ Wo,
    bf16* __restrict__ hsb, bf16* __restrict__ wqkv, bf16* __restrict__ wob)
{
    int i = (blockIdx.x * 256 + threadIdx.x) * 8;
    const float* src;
    bf16* dst;
    if (i < 4194304) {
        src = hs + i; dst = hsb + i;
    } else if (i < 7340032) {
        int off = i - 4194304;
        int which = off >> 20;           // 0=Wq 1=Wk 2=Wv
        int within = off & 1048575;
        src = (which == 0 ? Wq : which == 1 ? Wk : Wv) + within;
        dst = wqkv + off;
    } else {
        int off = i - 7340032;
        src = Wo + off; dst = wob + off;
    }
    float4 v0 = *(const float4*)src;
    float4 v1 = *(const float4*)(src + 4);
    bf16x8 o = { (bf16)v0.x, (bf16)v0.y, (bf16)v0.z, (bf16)v0.w,
                 (bf16)v1.x, (bf16)v1.y, (bf16)v1.z, (bf16)v1.w };
    *(bf16x8*)dst = o;
}

// ---------------------------------------------------------------------------
// Kernel 2 (R22): QKV projection, 128m x 96n tile -> grid 32x32 = 1024 blocks
// = exactly 4 blocks/CU = 16 waves/CU (was 768 = 3/CU = 12 waves/CU, the
// latency-exposed regime that cost attn 25% pre-R13). Waves 2x2, each 64x48,
// acc[4][3]. LDS 28KB -> 112KB at 4/CU. 2D XCD regions (8mx x 16ny): per-XCD
// L2 working set 8.75MB -> 5MB.
// ---------------------------------------------------------------------------
__global__ __launch_bounds__(256, 4) void gemm_bt(
    const bf16* __restrict__ A, const bf16* __restrict__ Bm,
    const float* __restrict__ b0, const float* __restrict__ b1,
    const float* __restrict__ b2,
    bf16* __restrict__ Qo, bf16* __restrict__ Ko, bf16* __restrict__ Vt)
{
    const int K = 1024;
    __shared__ __attribute__((aligned(16))) bf16 sA[128 * 64];   // 16KB
    __shared__ __attribute__((aligned(16))) bf16 sB[96 * 64];    // 12KB

    int tid = threadIdx.x;
    int wave = tid >> 6, lane = tid & 63;
    int quad = lane >> 4, l16 = lane & 15;
    // 2D XCD-region swizzle: xcd = orig&7 gets region (xcd&3, xcd>>2) of the
    // 32mx x 32ny grid; within-region c -> (c&7, c>>3). Bijective (1024%8==0).
    int orig = blockIdx.y * 32 + blockIdx.x;
    int xcd = orig & 7, c0 = orig >> 3;                 // c0 in [0,128)
    int mx = (xcd & 3) * 8 + (c0 & 7);                  // [0,32)
    int ny = (xcd >> 2) * 16 + (c0 >> 3);               // [0,32)
    int m0 = mx * 128;
    int n0 = ny * 96;
    int wm = (wave & 1) * 64, wn = (wave >> 1) * 48;
    int fs = l16 & 7;                   // read-side swizzle key (row&7 == l16&7)

    f32x4 acc[4][3];
#pragma unroll
    for (int i = 0; i < 4; i++)
#pragma unroll
        for (int j = 0; j < 3; j++) acc[i][j] = (f32x4){0.f, 0.f, 0.f, 0.f};

    for (int k0 = 0; k0 < K; k0 += 64) {
#pragma unroll
        for (int i = 0; i < 4; i++) {       // A: 1024 chunks (128 rows x 8)
            int c = tid + i * 256;
            int row = c >> 3;
            int kc = ((c & 7) ^ (row & 7)) * 8;   // swizzled source group
            gld_lds16(A + (size_t)(m0 + row) * K + k0 + kc, &sA[c * 8]);
        }
#pragma unroll
        for (int i = 0; i < 3; i++) {       // B: 768 chunks (96 rows x 8)
            int c = tid + i * 256;
            int row = c >> 3;
            int kc = ((c & 7) ^ (row & 7)) * 8;
            gld_lds16(Bm + (size_t)(n0 + row) * K + k0 + kc, &sB[c * 8]);
        }
        WAIT_VMCNT0();          // async LDS writes landed before barrier
        __syncthreads();

#pragma unroll
        for (int kp = 0; kp < 2; kp++) {     // two 32-col k-windows
            bf16x8 af[4], bfr[3];
#pragma unroll
            for (int i = 0; i < 4; i++)
                af[i] = *(const bf16x8*)&sA[(wm + i * 16 + l16) * 64 + (((kp * 4 + quad) ^ fs) * 8)];
#pragma unroll
            for (int j = 0; j < 3; j++)
                bfr[j] = *(const bf16x8*)&sB[(wn + j * 16 + l16) * 64 + (((kp * 4 + quad) ^ fs) * 8)];
#pragma unroll
            for (int i = 0; i < 4; i++)
#pragma unroll
                for (int j = 0; j < 3; j++)
                    acc[i][j] = __builtin_amdgcn_mfma_f32_16x16x32_bf16(
                        af[i], bfr[j], acc[i][j], 0, 0, 0);
        }
        __syncthreads();
    }

    // C/D layout: col = lane&15, row = quad*4 + reg  (m89/m91 verified)
    const float QSCALE = 0.125f * 1.44269504088896340736f;  // 1/sqrt(64)*log2(e)
#pragma unroll
    for (int j = 0; j < 3; j++) {
        int n = n0 + wn + j * 16 + l16;
        int region = n >> 10;            // uniform within j (base 16-aligned)
        int nn = n & 1023;
        int h = nn >> 6, d = nn & 63;
        float bias = (region == 0 ? b0 : region == 1 ? b1 : b2)[nn];
#pragma unroll
        for (int i = 0; i < 4; i++) {
            int mb = m0 + wm + i * 16 + quad * 4;     // 4-aligned, no 2048-cross
            int b = mb >> 11, s = mb & 2047;
            int bh = b * H_ + h;
            if (region == 2) {
                // packed V^T store: 4 consecutive s at fixed d (b64)
                bf16x4 pk = { f2bf(acc[i][j][0] + bias), f2bf(acc[i][j][1] + bias),
                              f2bf(acc[i][j][2] + bias), f2bf(acc[i][j][3] + bias) };
                *(bf16x4*)&Vt[((size_t)bh * DH_ + d) * S_ + s] = pk;
            } else {
#pragma unroll
                for (int r = 0; r < 4; r++) {
                    float v = acc[i][j][r] + bias;
                    if (region == 0)
                        Qo[((size_t)bh * S_ + s + r) * DH_ + d] = f2bf(v * QSCALE);
                    else
                        Ko[((size_t)bh * S_ + s + r) * DH_ + d] = f2bf(v);
                }
            }
        }
    }
}

// ---------------------------------------------------------------------------
// Kernel 4 (R21-verified 8-wave + R22 2D XCD regions): out = attn @ Wo^T + bo.
// 128m x 64n block, 512 threads, waves 4m x 2n each 32x32. 2D regions
// (8mx x 8ny): per-XCD L2 working set 8.25MB -> 3MB (fits 4MB L2).
// ---------------------------------------------------------------------------
__global__ __launch_bounds__(512, 4) void gemm_out(
    const bf16* __restrict__ A, const bf16* __restrict__ Bm,
    const float* __restrict__ bias0, float* __restrict__ Co)
{
    const int K = 1024;
    __shared__ __attribute__((aligned(16))) bf16 sA[128 * 64];   // 16KB
    __shared__ __attribute__((aligned(16))) bf16 sB[64 * 64];    // 8KB

    int tid = threadIdx.x;
    int wave = tid >> 6, lane = tid & 63;
    int quad = lane >> 4, l16 = lane & 15;
    // 2D XCD-region swizzle over the 32mx x 16ny grid (512 blocks, 64/XCD).
    int orig = blockIdx.y * 32 + blockIdx.x;
    int xcd = orig & 7, c0 = orig >> 3;                 // c0 in [0,64)
    int mx = (xcd & 3) * 8 + (c0 & 7);                  // [0,32)
    int ny = (xcd >> 2) * 8 + (c0 >> 3);                // [0,16)
    int m0 = mx * 128;
    int n0 = ny * 64;
    int wm = (wave & 3) * 32, wn = (wave >> 2) * 32;
    int fs = l16 & 7;

    f32x4 acc[2][2];
#pragma unroll
    for (int i = 0; i < 2; i++)
#pragma unroll
        for (int j = 0; j < 2; j++) acc[i][j] = (f32x4){0.f, 0.f, 0.f, 0.f};

    for (int k0 = 0; k0 < K; k0 += 64) {
#pragma unroll
        for (int i = 0; i < 2; i++) {        // A: 1024 chunks, 2/thread
            int c = tid + i * 512;
            int row = c >> 3;
            int kc = ((c & 7) ^ (row & 7)) * 8;
            gld_lds16(A + (size_t)(m0 + row) * K + k0 + kc, &sA[c * 8]);
        }
        {                                    // B: 512 chunks, 1/thread
            int c = tid;
            int row = c >> 3;                // rows 0..63
            int kc = ((c & 7) ^ (row & 7)) * 8;
            gld_lds16(Bm + (size_t)(n0 + row) * K + k0 + kc, &sB[c * 8]);
        }
        WAIT_VMCNT0();
        __syncthreads();

#pragma unroll
        for (int kp = 0; kp < 2; kp++) {
            bf16x8 af[2], bfr[2];
#pragma unroll
            for (int i = 0; i < 2; i++)
                af[i] = *(const bf16x8*)&sA[(wm + i * 16 + l16) * 64 + (((kp * 4 + quad) ^ fs) * 8)];
#pragma unroll
            for (int j = 0; j < 2; j++)
                bfr[j] = *(const bf16x8*)&sB[(wn + j * 16 + l16) * 64 + (((kp * 4 + quad) ^ fs) * 8)];
#pragma unroll
            for (int i = 0; i < 2; i++)
#pragma unroll
                for (int j = 0; j < 2; j++)
                    acc[i][j] = __builtin_amdgcn_mfma_f32_16x16x32_bf16(
                        af[i], bfr[j], acc[i][j], 0, 0, 0);
        }
        __syncthreads();
    }

#pragma unroll
    for (int j = 0; j < 2; j++) {
        int n = n0 + wn + j * 16 + l16;
        float bias = bias0[n];
#pragma unroll
        for (int i = 0; i < 2; i++)
#pragma unroll
            for (int r = 0; r < 4; r++) {
                int m = m0 + wm + i * 16 + quad * 4 + r;
                Co[(size_t)m * D_ + n] = acc[i][j][r] + bias;
            }
    }
}

// ---------------------------------------------------------------------------
// Kernel 3: flash attention — R19 BYTE-IDENTICAL (verified passing, 50.8us,
// FETCH 12.4MB). Loop+epilogue shape FROZEN per R16/R20 post-mortems.
// ---------------------------------------------------------------------------
__global__ __launch_bounds__(256, 4) void attn_kernel(
    const bf16* __restrict__ Q, const bf16* __restrict__ Kg,
    const bf16* __restrict__ Vt, const int* __restrict__ mask,
    bf16* __restrict__ Og)
{
    __shared__ __attribute__((aligned(16))) bf16 sK[128 * 64];        // [key][dh] 16KB
    __shared__ __attribute__((aligned(16))) bf16 sV[64 * 128];        // [d][key] 16KB
    __shared__ __attribute__((aligned(16))) unsigned short sMadd[S_]; // 4KB

    int tid = threadIdx.x;
    int wave = tid >> 6, lane = tid & 63;
    int quad = lane >> 4, l16 = lane & 15;
    // XCD-chunked swizzle: lid = bh*32 + qtile; each XCD gets 128 consecutive
    // lids = 4 full heads. 1024%8==0 -> bijective.
    int orig = blockIdx.y * 32 + blockIdx.x;
    int lid = (orig & 7) * 128 + (orig >> 3);
    int bh = lid >> 5;
    int q0 = (lid & 31) * 64;
    int b = bh >> 4;
    int f8 = l16 & 7;                          // sK read swizzle key
    int qh = wave & 1;                         // q-half (0/1), 32 q each
    int kh = wave >> 1;                        // key-half (0/1), 64 keys/iter each

    const bf16* Qb = Q + (size_t)bh * S_ * DH_;
    const bf16* Kb = Kg + (size_t)bh * S_ * DH_;
    const bf16* Vb = Vt + (size_t)bh * DH_ * S_;

    // expand mask row once per block: 1 -> 0x0000 (0.0f), 0 -> 0xF149 (-9.96e29)
    // 2048 entries / 256 threads = 8 each; published by the first loop barrier.
    {
        int base = b * S_ + tid * 8;
        int4 m0 = *(const int4*)&mask[base];
        int4 m1 = *(const int4*)&mask[base + 4];
        u16x4 e0 = { (unsigned short)(m0.x ? 0 : 0xF149),
                     (unsigned short)(m0.y ? 0 : 0xF149),
                     (unsigned short)(m0.z ? 0 : 0xF149),
                     (unsigned short)(m0.w ? 0 : 0xF149) };
        u16x4 e1 = { (unsigned short)(m1.x ? 0 : 0xF149),
                     (unsigned short)(m1.y ? 0 : 0xF149),
                     (unsigned short)(m1.z ? 0 : 0xF149),
                     (unsigned short)(m1.w ? 0 : 0xF149) };
        *(u16x4*)&sMadd[tid * 8] = e0;
        *(u16x4*)&sMadd[tid * 8 + 4] = e1;
    }

    // Q fragments for 2 q-tiles (B-operand; layout n=lane&15, k=quad*8+j)
    bf16x8 aq[2][2];
#pragma unroll
    for (int qt = 0; qt < 2; qt++) {
        int qrow = q0 + qh * 32 + qt * 16 + l16;
        aq[qt][0] = *(const bf16x8*)&Qb[(size_t)qrow * DH_ + quad * 8];
        aq[qt][1] = *(const bf16x8*)&Qb[(size_t)qrow * DH_ + 32 + quad * 8];
    }

    // ones B-fragment for row-sum MFMA
    const bf16 oneb = __builtin_bit_cast(bf16, (unsigned short)0x3F80);
    const bf16x8 ones = { oneb, oneb, oneb, oneb, oneb, oneb, oneb, oneb };

    f32x4 o[2][4];                       // o[qt][dt], C row=q, col=d
    f32x4 osum[2];                       // row-sums of P, C row=q (col dup'd)
#pragma unroll
    for (int i = 0; i < 2; i++) {
#pragma unroll
        for (int j = 0; j < 4; j++) o[i][j] = (f32x4){0.f, 0.f, 0.f, 0.f};
        osum[i] = (f32x4){0.f, 0.f, 0.f, 0.f};
    }

    for (int kt = 0; kt < S_; kt += 128) {
        // stage K[128k][64dh] + V^T[64d][128k]; source-col swizzled so the
        // lane-contiguous DMA dest gives conflict-free fragment reads.
#pragma unroll
        for (int i = 0; i < 8; i++) {
            int c = tid + i * 256;            // 0..2047
            if (c < 1024) {                   // K chunk: row=c>>3, group=c&7
                int row = c >> 3;
                int g = (c & 7) ^ (row & 7);
                gld_lds16(&Kb[(size_t)(kt + row) * DH_ + g * 8], &sK[c * 8]);
            } else {                          // V chunk: row=(c-1024)>>4, group=&15
                int cv = c - 1024;
                int row = cv >> 4;
                int g = (cv & 15) ^ (row & 15);
                gld_lds16(&Vb[(size_t)row * S_ + kt + g * 8], &sV[cv * 8]);
            }
        }
        WAIT_VMCNT0();
        __syncthreads();

#pragma unroll
        for (int pass = 0; pass < 2; pass++) {   // 32 keys per pass
            // --- S^T = K @ Q^T, P = exp2(S + maskadd), kept in registers ---
            unsigned w01[2][2], w23[2][2];       // [qt][mtl]: keys q'*4+{0,1}/{2,3}
#pragma unroll
            for (int mtl = 0; mtl < 2; mtl++) {
                int keyrow = kh * 64 + pass * 32 + mtl * 16;   // wave-local tile base
                bf16x8 ak0 = *(const bf16x8*)&sK[(keyrow + l16) * 64 + ((quad ^ f8) * 8)];
                bf16x8 ak1 = *(const bf16x8*)&sK[(keyrow + l16) * 64 + (((quad + 4) ^ f8) * 8)];
                u16x4 mm = *(const u16x4*)&sMadd[kt + keyrow + quad * 4];
                // mask-add as MFMA C-init (per key == per C row)
                f32x4 cinit;
                cinit[0] = __builtin_bit_cast(float, (unsigned)mm.x << 16);
                cinit[1] = __builtin_bit_cast(float, (unsigned)mm.y << 16);
                cinit[2] = __builtin_bit_cast(float, (unsigned)mm.z << 16);
                cinit[3] = __builtin_bit_cast(float, (unsigned)mm.w << 16);
#pragma unroll
                for (int qt = 0; qt < 2; qt++) {
                    f32x4 c = cinit;
                    c = __builtin_amdgcn_mfma_f32_16x16x32_bf16(ak0, aq[qt][0], c, 0, 0, 0);
                    c = __builtin_amdgcn_mfma_f32_16x16x32_bf16(ak1, aq[qt][1], c, 0, 0, 0);
                    float p0 = __builtin_amdgcn_exp2f(c[0]);
                    float p1 = __builtin_amdgcn_exp2f(c[1]);
                    float p2 = __builtin_amdgcn_exp2f(c[2]);
                    float p3 = __builtin_amdgcn_exp2f(c[3]);
                    w01[qt][mtl] = cvtpk(p0, p1);
                    w23[qt][mtl] = cvtpk(p2, p3);
                }
            }

            // --- in-register remap (R13-verified): -> PV A-frag words ---
            bf16x8 ap[2];
#pragma unroll
            for (int qt = 0; qt < 2; qt++) {
                unsigned r0 = w01[qt][0], r2 = w01[qt][1];     // j=0 pair
                pl32swap(r0, r2); pl16swap(r0, r2);            // -> word0, word2
                unsigned r1 = w23[qt][0], r3 = w23[qt][1];     // j=1 pair
                pl32swap(r1, r3); pl16swap(r1, r3);            // -> word1, word3
                union { unsigned u[4]; bf16x8 v; } U;
                U.u[0] = r0; U.u[1] = r1; U.u[2] = r2; U.u[3] = r3;
                ap[qt] = U.v;
                // row-sums: osum[qt] += P @ ones  (replaces scalar psum adds)
                osum[qt] = __builtin_amdgcn_mfma_f32_16x16x32_bf16(ap[qt], ones, osum[qt], 0, 0, 0);
            }

            // --- O += P @ V (A=P[q][k32] in regs, B=V^T[d][k32]) ---
#pragma unroll
            for (int dt = 0; dt < 4; dt++) {
                int g = (kh * 8 + pass * 4 + quad) ^ l16;      // sV group slot
                bf16x8 bv = *(const bf16x8*)&sV[(dt * 16 + l16) * 128 + g * 8];
#pragma unroll
                for (int qt = 0; qt < 2; qt++)
                    o[qt][dt] = __builtin_amdgcn_mfma_f32_16x16x32_bf16(ap[qt], bv, o[qt][dt], 0, 0, 0);
            }
        }
        __syncthreads();   // all fragment reads done before next staging
    }

    // cross-wave reduction: waves 2,3 (key-half 1) hand partials (o + osum)
    // to waves 0,1. Slots 0..7 = o[qt][dt], slots 8..9 = osum[qt].
    float* sRed = (wave == 2) ? (float*)sK : (float*)sV;   // 16KB each, 10KB used
    if (wave >= 2) {
#pragma unroll
        for (int qt = 0; qt < 2; qt++) {
#pragma unroll
            for (int dt = 0; dt < 4; dt++)
                *(f32x4*)&sRed[((qt * 4 + dt) * 64 + lane) * 4] = o[qt][dt];
            *(f32x4*)&sRed[((8 + qt) * 64 + lane) * 4] = osum[qt];
        }
    }
    __syncthreads();
    if (wave < 2) {
        float* src = (wave == 0) ? (float*)sK : (float*)sV;
#pragma unroll
        for (int qt = 0; qt < 2; qt++) {
#pragma unroll
            for (int dt = 0; dt < 4; dt++)
                o[qt][dt] += *(const f32x4*)&src[((qt * 4 + dt) * 64 + lane) * 4];
            osum[qt] += *(const f32x4*)&src[((8 + qt) * 64 + lane) * 4];
        }
        int h = bh & 15;
#pragma unroll
        for (int qt = 0; qt < 2; qt++) {
            // osum reg r holds full psum for q = qt*16 + quad*4 + r (cols dup)
            float rcp[4] = { 1.f / osum[qt][0], 1.f / osum[qt][1],
                             1.f / osum[qt][2], 1.f / osum[qt][3] };
#pragma unroll
            for (int r = 0; r < 4; r++) {
                int s = q0 + wave * 32 + qt * 16 + quad * 4 + r;   // qh==wave here
#pragma unroll
                for (int dt = 0; dt < 4; dt++) {
                    int d = dt * 16 + l16;
                    Og[((size_t)(b * S_ + s)) * D_ + h * 64 + d] = f2bf(o[qt][dt][r] * rcp[r]);
                }
            }
        }
    }
}

// ---------------------------------------------------------------------------
extern "C" void kernel_launch(void* const* d_in, const int* in_sizes, int n_in,
                              void* d_out, int out_size, void* d_ws, size_t ws_size,
                              hipStream_t stream) {
    const float* hs = (const float*)d_in[0];
    const int* mask = (const int*)d_in[1];
    const float* Wq = (const float*)d_in[2];
    const float* bq = (const float*)d_in[3];
    const float* Wk = (const float*)d_in[4];
    const float* bk = (const float*)d_in[5];
    const float* Wv = (const float*)d_in[6];
    const float* bv = (const float*)d_in[7];
    const float* Wo = (const float*)d_in[8];
    const float* bo = (const float*)d_in[9];
    float* out = (float*)d_out;

    char* ws = (char*)d_ws;
    bf16* hsb  = (bf16*)(ws);                          // 8 MB (4096x1024)
    bf16* wqkv = (bf16*)(ws + ((size_t)8 << 20));      // 6 MB (3072x1024)
    bf16* wob  = (bf16*)(ws + ((size_t)14 << 20));     // 2 MB (1024x1024)
    bf16* Qw   = (bf16*)(ws + ((size_t)16 << 20));     // 8 MB (b,h,s,d)
    bf16* Kw   = (bf16*)(ws + ((size_t)24 << 20));     // 8 MB (b,h,s,d)
    bf16* Vtw  = (bf16*)(ws + ((size_t)32 << 20));     // 8 MB (b,h,d,s)
    bf16* attn = (bf16*)(ws + ((size_t)40 << 20));     // 8 MB (b,s,h*64+d)

    cvt_kernel<<<4096, 256, 0, stream>>>(hs, Wq, Wk, Wv, Wo, hsb, wqkv, wob);
    gemm_bt<<<dim3(32, 32), 256, 0, stream>>>(hsb, wqkv, bq, bk, bv,
                                              Qw, Kw, Vtw);
    attn_kernel<<<dim3(32, 32), 256, 0, stream>>>(Qw, Kw, Vtw, mask, attn);
    gemm_out<<<dim3(32, 16), 512, 0, stream>>>(attn, wob, bo, out);
}